// Round 2
// baseline (973.791 us; speedup 1.0000x reference)
//
#include <hip/hip_runtime.h>
#include <math.h>

// Actor_att1 on gfx950 — MFMA restructure.
// One wave processes 16 rows. All five MLP layers run as transposed GEMMs on
// v_mfma_f32_16x16x16_f16: D = W^T (A) x X^T (B), N-dim = entity (per row) or
// row (batched). D layout (col=lane&15,row=4*(lane>>4)+reg; m89-verified)
// equals B layout of the K=16 shape (n=lane&15,k=4*(lane>>4)+j), so layer
// outputs chain into the next layer's B operand entirely in registers.
// Softmax / LayerNorm glue in fp32 with __shfl_xor butterflies.

#define OBS 127
#define XS_STRIDE 128   // f16 elems per row in LDS
#define SL_STRIDE 24    // fp32 stride for self_lds (16B-aligned rows, bank-spread)

typedef _Float16 v4h __attribute__((ext_vector_type(4)));
typedef float    v4f __attribute__((ext_vector_type(4)));

#define MFMA(a, b, c) __builtin_amdgcn_mfma_f32_16x16x16f16((a), (b), (c), 0, 0, 0)

union HU { uint2 u; v4h h; };

__device__ __forceinline__ v4h zero4h() {
    v4h z; z[0] = z[1] = z[2] = z[3] = (_Float16)0.f; return z;
}
// A-fragment for transposed weight: A[m=co+(lane&15)][k=k0+4*(lane>>4)+j] = W[k*ncols+co+m]
__device__ __forceinline__ v4h afragT(const float* __restrict__ W, int ncols, int co,
                                      int kin, int k0, int lane, int colmax) {
    const int mm = lane & 15, gg = lane >> 4;
    v4h r;
    #pragma unroll
    for (int j = 0; j < 4; ++j) {
        const int k = k0 + 4 * gg + j;
        const float v = (k < kin && (co + mm) < colmax) ? W[k * ncols + co + mm] : 0.f;
        r[j] = (_Float16)v;
    }
    return r;
}
__device__ __forceinline__ v4f bfrag4(const float* __restrict__ b, int gg) {
    const float4 t = *(const float4*)(b + 4 * gg);
    v4f r; r[0] = t.x; r[1] = t.y; r[2] = t.z; r[3] = t.w; return r;
}
__device__ __forceinline__ v4h packR(v4f d) {   // relu + cvt f16
    v4h r;
    #pragma unroll
    for (int j = 0; j < 4; ++j) r[j] = (_Float16)fmaxf(d[j], 0.f);
    return r;
}
__device__ __forceinline__ v4h packL(v4f d) {   // leaky-relu(0.01) + cvt f16
    v4h r;
    #pragma unroll
    for (int j = 0; j < 4; ++j) { const float a = d[j]; r[j] = (_Float16)fmaxf(a, 0.01f * a); }
    return r;
}
__device__ __forceinline__ v4f relu4(v4f d) {
    v4f r;
    #pragma unroll
    for (int j = 0; j < 4; ++j) r[j] = fmaxf(d[j], 0.f);
    return r;
}

// Per-branch entity pipeline over the wave's 16 rows.
// BR=0: other (15 entities, 5 features). BR=1: food (16 entities, 3 features).
// Returns the merge-GEMM B-fragment (lane m holds row m's branch output, k=4g+j).
template <int BR>
__device__ __forceinline__ v4h branch_rows(const _Float16* __restrict__ xs,
                                           const float* __restrict__ slds,
                                           v4h w1t0, v4h w1t1, v4h w2k0, v4h w2k1,
                                           v4f b1t0, v4f b1t1, v4f b2f,
                                           v4f gf, v4f bfv, int lane) {
    const int mm = lane & 15, gg = lane >> 4;
    v4h cap = zero4h();
    for (int rho = 0; rho < 16; ++rho) {
        // B1 fragment: B[k=feat][n=entity=mm] from staged obs of row rho
        v4h bfr = zero4h();
        if (BR == 0) {
            if (gg == 0 && mm < 15) {             // k=0..3: pos.xy, vel.xy
                HU u;
                u.u.x = *(const unsigned*)(xs + rho * XS_STRIDE + 4 + 2 * mm);
                u.u.y = *(const unsigned*)(xs + rho * XS_STRIDE + 34 + 2 * mm);
                bfr = u.h;
            } else if (gg == 1 && mm < 15) {      // k=4: scal
                bfr[0] = xs[rho * XS_STRIDE + 64 + mm];
            }
        } else {
            if (gg == 0) {                        // k=0..2: food triple
                bfr[0] = xs[rho * XS_STRIDE + 79 + 3 * mm];
                bfr[1] = xs[rho * XS_STRIDE + 80 + 3 * mm];
                bfr[2] = xs[rho * XS_STRIDE + 81 + 3 * mm];
            }
        }
        // layer1: H^T (32ch) = two 16-ch tiles, bias via C
        const v4f d0 = MFMA(w1t0, bfr, b1t0);
        const v4f d1 = MFMA(w1t1, bfr, b1t1);
        // layer2: enc^T = W2^T (A) x relu(H^T) (B = D directly)
        v4f e2 = MFMA(w2k0, packR(d0), b2f);
        e2 = MFMA(w2k1, packR(d1), e2);
        e2 = relu4(e2);   // lane holds enc[e=mm][ch=4g+r]

        // scores: dot(self[rho], enc[e]) over 16 ch (4 lane-groups)
        const float4 sv = *(const float4*)(slds + rho * SL_STRIDE + 4 * gg);
        float part = sv.x * e2[0] + sv.y * e2[1] + sv.z * e2[2] + sv.w * e2[3];
        part += __shfl_xor(part, 16);
        part += __shfl_xor(part, 32);
        float s = (BR == 0 && mm == 15) ? -3.0e38f : part * 0.25f;
        float mx = s;
        #pragma unroll
        for (int d = 1; d < 16; d <<= 1) mx = fmaxf(mx, __shfl_xor(mx, d));
        const float p = __expf(s - mx);
        float l = p;
        #pragma unroll
        for (int d = 1; d < 16; d <<= 1) l += __shfl_xor(l, d);
        const float w = p / l;
        // attended = sum_e w[e]*enc[e][ch]: reduce over e-lanes (bits 0..3)
        float t0 = w * e2[0], t1 = w * e2[1], t2 = w * e2[2], t3 = w * e2[3];
        #pragma unroll
        for (int d = 1; d < 16; d <<= 1) {
            t0 += __shfl_xor(t0, d);
            t1 += __shfl_xor(t1, d);
            t2 += __shfl_xor(t2, d);
            t3 += __shfl_xor(t3, d);
        }
        // LayerNorm over 16 ch (sum across 4 lane-groups), + affine + relu
        float loc = t0 + t1 + t2 + t3;
        loc += __shfl_xor(loc, 16); loc += __shfl_xor(loc, 32);
        const float mu = loc * 0.0625f;
        const float e0 = t0 - mu, e1 = t1 - mu, e2c = t2 - mu, e3 = t3 - mu;
        float vv = e0 * e0 + e1 * e1 + e2c * e2c + e3 * e3;
        vv += __shfl_xor(vv, 16); vv += __shfl_xor(vv, 32);
        const float inv = rsqrtf(vv * 0.0625f + 1e-5f);
        v4h pk;
        pk[0] = (_Float16)fmaxf(e0 * inv * gf[0] + bfv[0], 0.f);
        pk[1] = (_Float16)fmaxf(e1 * inv * gf[1] + bfv[1], 0.f);
        pk[2] = (_Float16)fmaxf(e2c * inv * gf[2] + bfv[2], 0.f);
        pk[3] = (_Float16)fmaxf(e3 * inv * gf[3] + bfv[3], 0.f);
        if (mm == rho) cap = pk;   // capture into merge B-frag (n=row)
    }
    return cap;
}

__global__ __launch_bounds__(256)
void actor_mfma(const float* __restrict__ x,
                const float* __restrict__ en_w1, const float* __restrict__ en_b1,
                const float* __restrict__ en_w2, const float* __restrict__ en_b2,
                const float* __restrict__ oa_w1, const float* __restrict__ oa_b1,
                const float* __restrict__ oa_w2, const float* __restrict__ oa_b2,
                const float* __restrict__ oa_g,  const float* __restrict__ oa_bln,
                const float* __restrict__ g_w1,  const float* __restrict__ g_b1,
                const float* __restrict__ g_w2,  const float* __restrict__ g_b2,
                const float* __restrict__ g_g,   const float* __restrict__ g_bln,
                const float* __restrict__ m_w1,  const float* __restrict__ m_b1,
                const float* __restrict__ m_w2,  const float* __restrict__ m_b2,
                const float* __restrict__ m_w3,  const float* __restrict__ m_b3,
                float* __restrict__ out, int B)
{
    const int lane = threadIdx.x & 63, wid = threadIdx.x >> 6;
    const int mm = lane & 15, gg = lane >> 4;

    __shared__ __align__(16) _Float16 xs_all[4][16 * XS_STRIDE];
    __shared__ __align__(16) float    sl_all[4][16 * SL_STRIDE];
    _Float16* xs = xs_all[wid];
    float*    slds = sl_all[wid];

    for (int grp = 0; grp < 2; ++grp) {
        const int r0 = (blockIdx.x * 8 + wid * 2 + grp) * 16;
        const bool valid = (r0 < B);

        // ---- stage 16 rows of obs into LDS as f16 (coalesced) ----
        if (valid) {
            const float* __restrict__ xp = x + (size_t)r0 * OBS;
            const int lim = (r0 + 16 <= B) ? 2032 : (B - r0) * OBS;
            #pragma unroll
            for (int i = 0; i < 32; ++i) {
                const int f = i * 64 + lane;
                if (f < lim) {
                    const int r = f / 127;         // const-div -> mul_hi
                    xs[f + r] = (_Float16)xp[f];   // row-stride 128
                }
            }
        }
        __syncthreads();

        v4h Bself = zero4h(), Bfood = zero4h(), Bother = zero4h();
        if (valid) {
            // ---- self encoder (batched over 16 rows, N=row) ----
            {
                const v4h ew1t0 = afragT(en_w1, 32, 0, 4, 0, lane, 32);
                const v4h ew1t1 = afragT(en_w1, 32, 16, 4, 0, lane, 32);
                const v4h ew2k0 = afragT(en_w2, 16, 0, 32, 0, lane, 16);
                const v4h ew2k1 = afragT(en_w2, 16, 0, 32, 16, lane, 16);
                const v4f eb1t0 = bfrag4(en_b1, gg);
                const v4f eb1t1 = bfrag4(en_b1 + 16, gg);
                const v4f eb2 = bfrag4(en_b2, gg);
                v4h bs = zero4h();
                if (gg == 0) bs = *(const v4h*)(xs + mm * XS_STRIDE);  // xr[0..3]
                const v4f h0 = MFMA(ew1t0, bs, eb1t0);
                const v4f h1 = MFMA(ew1t1, bs, eb1t1);
                v4f st = MFMA(ew2k0, packR(h0), eb2);
                st = MFMA(ew2k1, packR(h1), st);
                st = relu4(st);                 // self^T[ch=4g+r][row=mm]
                Bself = packR(st);              // already >=0; plain cvt
                float4 sv; sv.x = st[0]; sv.y = st[1]; sv.z = st[2]; sv.w = st[3];
                *(float4*)(slds + mm * SL_STRIDE + 4 * gg) = sv;
            }
        }
        __syncthreads();
        if (valid) {
            // ---- other-agent branch ----
            {
                const v4h w1t0 = afragT(oa_w1, 32, 0, 5, 0, lane, 32);
                const v4h w1t1 = afragT(oa_w1, 32, 16, 5, 0, lane, 32);
                const v4h w2k0 = afragT(oa_w2, 16, 0, 32, 0, lane, 16);
                const v4h w2k1 = afragT(oa_w2, 16, 0, 32, 16, lane, 16);
                Bother = branch_rows<0>(xs, slds, w1t0, w1t1, w2k0, w2k1,
                                        bfrag4(oa_b1, gg), bfrag4(oa_b1 + 16, gg),
                                        bfrag4(oa_b2, gg), bfrag4(oa_g, gg),
                                        bfrag4(oa_bln, gg), lane);
            }
            // ---- food branch ----
            {
                const v4h w1t0 = afragT(g_w1, 32, 0, 3, 0, lane, 32);
                const v4h w1t1 = afragT(g_w1, 32, 16, 3, 0, lane, 32);
                const v4h w2k0 = afragT(g_w2, 16, 0, 32, 0, lane, 16);
                const v4h w2k1 = afragT(g_w2, 16, 0, 32, 16, lane, 16);
                Bfood = branch_rows<1>(xs, slds, w1t0, w1t1, w2k0, w2k1,
                                       bfrag4(g_b1, gg), bfrag4(g_b1 + 16, gg),
                                       bfrag4(g_b2, gg), bfrag4(g_g, gg),
                                       bfrag4(g_bln, gg), lane);
            }
            // ---- merge MLP (batched, N=row): 48 -> 32 -> 32 -> 2, tanh ----
            {
                v4f h1t0 = bfrag4(m_b1, gg);
                v4f h1t1 = bfrag4(m_b1 + 16, gg);
                h1t0 = MFMA(afragT(m_w1, 32, 0, 48, 0, lane, 32), Bself, h1t0);
                h1t0 = MFMA(afragT(m_w1, 32, 0, 48, 16, lane, 32), Bfood, h1t0);
                h1t0 = MFMA(afragT(m_w1, 32, 0, 48, 32, lane, 32), Bother, h1t0);
                h1t1 = MFMA(afragT(m_w1, 32, 16, 48, 0, lane, 32), Bself, h1t1);
                h1t1 = MFMA(afragT(m_w1, 32, 16, 48, 16, lane, 32), Bfood, h1t1);
                h1t1 = MFMA(afragT(m_w1, 32, 16, 48, 32, lane, 32), Bother, h1t1);
                const v4h q0 = packL(h1t0), q1 = packL(h1t1);
                v4f h2t0 = bfrag4(m_b2, gg);
                v4f h2t1 = bfrag4(m_b2 + 16, gg);
                h2t0 = MFMA(afragT(m_w2, 32, 0, 32, 0, lane, 32), q0, h2t0);
                h2t0 = MFMA(afragT(m_w2, 32, 0, 32, 16, lane, 32), q1, h2t0);
                h2t1 = MFMA(afragT(m_w2, 32, 16, 32, 0, lane, 32), q0, h2t1);
                h2t1 = MFMA(afragT(m_w2, 32, 16, 32, 16, lane, 32), q1, h2t1);
                const v4h z0 = packL(h2t0), z1 = packL(h2t1);
                v4f ob; ob[0] = ob[1] = ob[2] = ob[3] = 0.f;
                if (gg == 0) { ob[0] = m_b3[0]; ob[1] = m_b3[1]; }
                v4f oo = MFMA(afragT(m_w3, 2, 0, 32, 0, lane, 2), z0, ob);
                oo = MFMA(afragT(m_w3, 2, 0, 32, 16, lane, 2), z1, oo);
                if (gg == 0 && r0 + mm < B) {
                    float2 res;
                    res.x = tanhf(oo[0]);
                    res.y = tanhf(oo[1]);
                    *(float2*)(out + (size_t)(r0 + mm) * 2) = res;
                }
            }
        }
        __syncthreads();
    }
}

extern "C" void kernel_launch(void* const* d_in, const int* in_sizes, int n_in,
                              void* d_out, int out_size, void* d_ws, size_t ws_size,
                              hipStream_t stream) {
    const int B = in_sizes[0] / OBS;
    const float* xin = (const float*)d_in[0];
    const float* en_w1 = (const float*)d_in[1];
    const float* en_b1 = (const float*)d_in[2];
    const float* en_w2 = (const float*)d_in[3];
    const float* en_b2 = (const float*)d_in[4];
    const float* oa_w1 = (const float*)d_in[5];
    const float* oa_b1 = (const float*)d_in[6];
    const float* oa_w2 = (const float*)d_in[7];
    const float* oa_b2 = (const float*)d_in[8];
    const float* oa_g  = (const float*)d_in[9];
    const float* oa_bl = (const float*)d_in[10];
    const float* g_w1  = (const float*)d_in[11];
    const float* g_b1  = (const float*)d_in[12];
    const float* g_w2  = (const float*)d_in[13];
    const float* g_b2  = (const float*)d_in[14];
    const float* g_g   = (const float*)d_in[15];
    const float* g_bl  = (const float*)d_in[16];
    const float* m_w1  = (const float*)d_in[17];
    const float* m_b1  = (const float*)d_in[18];
    const float* m_w2  = (const float*)d_in[19];
    const float* m_b2  = (const float*)d_in[20];
    const float* m_w3  = (const float*)d_in[21];
    const float* m_b3  = (const float*)d_in[22];

    const int rows_per_block = 128;  // 4 waves x 2 groups x 16 rows
    const int grid = (B + rows_per_block - 1) / rows_per_block;
    actor_mfma<<<grid, 256, 0, stream>>>(
        xin, en_w1, en_b1, en_w2, en_b2,
        oa_w1, oa_b1, oa_w2, oa_b2, oa_g, oa_bl,
        g_w1, g_b1, g_w2, g_b2, g_g, g_bl,
        m_w1, m_b1, m_w2, m_b2, m_w3, m_b3,
        (float*)d_out, B);
}

// Round 3
// 385.404 us; speedup vs baseline: 2.5267x; 2.5267x over previous
//
#include <hip/hip_runtime.h>
#include <math.h>

// Actor_att1 on gfx950 — MFMA, row-tiled (R3).
// One wave = 16 rows. Entity encoders tiled with N=row (one entity per step):
// layer2 D layout (col=lane&15=row, reg=channel) keeps each row's enc in the
// lane that owns the row -> in-lane online softmax, 2 shuffles per entity.
// Self/branch outputs land directly in merge-GEMM B-fragment layout.
// Fragment conventions HW-validated by R2 (passed, absmax 1.95e-3).

#define OBS 127
#define XSS 132   // f16 LDS row stride: 132*2B=264B=66 dwords -> row r hits bank (66r)%32=2r (distinct)

typedef _Float16 v4h __attribute__((ext_vector_type(4)));
typedef float    v4f __attribute__((ext_vector_type(4)));

#define MFMA(a, b, c) __builtin_amdgcn_mfma_f32_16x16x16f16((a), (b), (c), 0, 0, 0)

union HU { unsigned u[2]; v4h h; };

__device__ __forceinline__ v4h zero4h() {
    v4h z; z[0] = z[1] = z[2] = z[3] = (_Float16)0.f; return z;
}
// A-fragment of transposed weight: A[m=co+(lane&15)][k=k0+4*(lane>>4)+j] = W[k*ncols+co+m]
__device__ __forceinline__ v4h afragT(const float* __restrict__ W, int ncols, int co,
                                      int kin, int k0, int lane, int colmax) {
    const int mm = lane & 15, gg = lane >> 4;
    v4h r;
    #pragma unroll
    for (int j = 0; j < 4; ++j) {
        const int k = k0 + 4 * gg + j;
        const float v = (k < kin && (co + mm) < colmax) ? W[k * ncols + co + mm] : 0.f;
        r[j] = (_Float16)v;
    }
    return r;
}
__device__ __forceinline__ v4f bfrag4(const float* __restrict__ b, int gg) {
    const float4 t = *(const float4*)(b + 4 * gg);
    v4f r; r[0] = t.x; r[1] = t.y; r[2] = t.z; r[3] = t.w; return r;
}
__device__ __forceinline__ v4h packR(v4f d) {   // relu + cvt f16
    v4h r;
    #pragma unroll
    for (int j = 0; j < 4; ++j) r[j] = (_Float16)fmaxf(d[j], 0.f);
    return r;
}
__device__ __forceinline__ v4h packL(v4f d) {   // leaky-relu(0.01) + cvt f16
    v4h r;
    #pragma unroll
    for (int j = 0; j < 4; ++j) { const float a = d[j]; r[j] = (_Float16)fmaxf(a, 0.01f * a); }
    return r;
}
__device__ __forceinline__ v4f relu4(v4f d) {
    v4f r;
    #pragma unroll
    for (int j = 0; j < 4; ++j) r[j] = fmaxf(d[j], 0.f);
    return r;
}

// Entity branch, row-tiled. BR=0: other (15 ents, 5 feat). BR=1: food (16 ents, 3 feat).
// st = this lane's self_out[row=mm][ch=4gg+r]. Returns merge B-fragment.
template <int BR>
__device__ __forceinline__ v4h branch_rows(const _Float16* __restrict__ xs, v4f st,
                                           v4h w1t0, v4h w1t1, v4h w2k0, v4h w2k1,
                                           v4f b1t0, v4f b1t1, v4f b2f,
                                           v4f gf, v4f bfv, int lane) {
    const int mm = lane & 15, gg = lane >> 4;
    const int NE = (BR == 0) ? 15 : 16;
    float m = -3.0e38f, l = 0.f;
    float o0 = 0.f, o1 = 0.f, o2 = 0.f, o3 = 0.f;
    const _Float16* xr = xs + mm * XSS;

    for (int e = 0; e < NE; ++e) {
        // B-frag: B[k=feat][n=row=mm], features of entity e of this lane's row
        v4h bfr = zero4h();
        if (BR == 0) {
            if (gg == 0) {
                HU u;
                u.u[0] = *(const unsigned*)(xr + 4 + 2 * e);    // pos.xy (even offset)
                u.u[1] = *(const unsigned*)(xr + 34 + 2 * e);   // vel.xy
                bfr = u.h;
            } else if (gg == 1) {
                bfr[0] = xr[64 + e];                            // scal
            }
        } else {
            if (gg == 0) {
                bfr[0] = xr[79 + 3 * e];
                bfr[1] = xr[80 + 3 * e];
                bfr[2] = xr[81 + 3 * e];
            }
        }
        // layer1 (two 16-ch tiles, bias in C), layer2 (K=32), relu
        const v4f d0 = MFMA(w1t0, bfr, b1t0);
        const v4f d1 = MFMA(w1t1, bfr, b1t1);
        v4f e2 = MFMA(w2k0, packR(d0), b2f);
        e2 = MFMA(w2k1, packR(d1), e2);
        e2 = relu4(e2);   // enc[e][row=mm][ch=4gg+r]

        // score: dot(self[row], enc[e][row]) over 16ch = in-lane quad + gg-reduce
        float part = st[0] * e2[0] + st[1] * e2[1] + st[2] * e2[2] + st[3] * e2[3];
        part += __shfl_xor(part, 16);
        part += __shfl_xor(part, 32);
        const float s = part * 0.25f;
        // online softmax (in-lane, one exp)
        const float d = m - s;
        const float mn = fmaxf(m, s);
        const float ee = __expf(-fabsf(d));
        const float sc = (d < 0.f) ? ee : 1.f;   // exp(m-mn)
        const float p  = (d < 0.f) ? 1.f : ee;   // exp(s-mn)
        l = l * sc + p;
        o0 = o0 * sc + p * e2[0];
        o1 = o1 * sc + p * e2[1];
        o2 = o2 * sc + p * e2[2];
        o3 = o3 * sc + p * e2[3];
        m = mn;
    }
    // normalize + LayerNorm(16ch) + affine + relu
    const float rl = 1.f / l;
    o0 *= rl; o1 *= rl; o2 *= rl; o3 *= rl;
    float sum = o0 + o1 + o2 + o3;
    sum += __shfl_xor(sum, 16); sum += __shfl_xor(sum, 32);
    const float mu = sum * 0.0625f;
    const float e0 = o0 - mu, e1 = o1 - mu, e2c = o2 - mu, e3 = o3 - mu;
    float vv = e0 * e0 + e1 * e1 + e2c * e2c + e3 * e3;
    vv += __shfl_xor(vv, 16); vv += __shfl_xor(vv, 32);
    const float inv = rsqrtf(vv * 0.0625f + 1e-5f);
    v4h pk;
    pk[0] = (_Float16)fmaxf(e0 * inv * gf[0] + bfv[0], 0.f);
    pk[1] = (_Float16)fmaxf(e1 * inv * gf[1] + bfv[1], 0.f);
    pk[2] = (_Float16)fmaxf(e2c * inv * gf[2] + bfv[2], 0.f);
    pk[3] = (_Float16)fmaxf(e3 * inv * gf[3] + bfv[3], 0.f);
    return pk;   // B[k=4gg+j][n=row=mm] for the merge GEMM
}

__device__ __forceinline__ float fast_tanh(float x) {
    x = fminf(fmaxf(x, -15.f), 15.f);
    const float ex = __expf(2.f * x);
    return (ex - 1.f) / (ex + 1.f);
}

__global__ __launch_bounds__(256)
void actor_mfma(const float* __restrict__ x,
                const float* __restrict__ en_w1, const float* __restrict__ en_b1,
                const float* __restrict__ en_w2, const float* __restrict__ en_b2,
                const float* __restrict__ oa_w1, const float* __restrict__ oa_b1,
                const float* __restrict__ oa_w2, const float* __restrict__ oa_b2,
                const float* __restrict__ oa_g,  const float* __restrict__ oa_bln,
                const float* __restrict__ g_w1,  const float* __restrict__ g_b1,
                const float* __restrict__ g_w2,  const float* __restrict__ g_b2,
                const float* __restrict__ g_g,   const float* __restrict__ g_bln,
                const float* __restrict__ m_w1,  const float* __restrict__ m_b1,
                const float* __restrict__ m_w2,  const float* __restrict__ m_b2,
                const float* __restrict__ m_w3,  const float* __restrict__ m_b3,
                float* __restrict__ out, int B)
{
    const int lane = threadIdx.x & 63, wid = threadIdx.x >> 6;
    const int mm = lane & 15, gg = lane >> 4;

    __shared__ __align__(16) _Float16 xs_all[4][16 * XSS];
    _Float16* xs = xs_all[wid];

    const int r0 = blockIdx.x * 64 + wid * 16;

    // ---- stage this wave's 16 rows into LDS as f16 (coalesced reads) ----
    {
        const float* __restrict__ xp = x + (size_t)r0 * OBS;
        const int lim = (r0 + 16 <= B) ? 2032 : ((B > r0) ? (B - r0) * OBS : 0);
        #pragma unroll
        for (int i = 0; i < 32; ++i) {
            const int f = i * 64 + lane;
            if (f < lim) {
                const int r = f / 127;           // const-div
                xs[f + 5 * r] = (_Float16)xp[f]; // row*132 + col
            }
        }
    }

    // ---- weight/bias fragments (L1-hot, loaded once) ----
    const v4h ew1t0 = afragT(en_w1, 32, 0, 4, 0, lane, 32);
    const v4h ew1t1 = afragT(en_w1, 32, 16, 4, 0, lane, 32);
    const v4h ew2k0 = afragT(en_w2, 16, 0, 32, 0, lane, 16);
    const v4h ew2k1 = afragT(en_w2, 16, 0, 32, 16, lane, 16);
    const v4f eb1t0 = bfrag4(en_b1, gg);
    const v4f eb1t1 = bfrag4(en_b1 + 16, gg);
    const v4f eb2   = bfrag4(en_b2, gg);

    const v4h ow1t0 = afragT(oa_w1, 32, 0, 5, 0, lane, 32);
    const v4h ow1t1 = afragT(oa_w1, 32, 16, 5, 0, lane, 32);
    const v4h ow2k0 = afragT(oa_w2, 16, 0, 32, 0, lane, 16);
    const v4h ow2k1 = afragT(oa_w2, 16, 0, 32, 16, lane, 16);

    const v4h fw1t0 = afragT(g_w1, 32, 0, 3, 0, lane, 32);
    const v4h fw1t1 = afragT(g_w1, 32, 16, 3, 0, lane, 32);
    const v4h fw2k0 = afragT(g_w2, 16, 0, 32, 0, lane, 16);
    const v4h fw2k1 = afragT(g_w2, 16, 0, 32, 16, lane, 16);

    __syncthreads();

    // ---- self encoder (N=row): lane holds self[row=mm][ch=4gg+r] ----
    v4h bs = zero4h();
    if (gg == 0) bs = *(const v4h*)(xs + mm * XSS);   // xr[0..3]
    const v4f h0 = MFMA(ew1t0, bs, eb1t0);
    const v4f h1 = MFMA(ew1t1, bs, eb1t1);
    v4f st = MFMA(ew2k0, packR(h0), eb2);
    st = MFMA(ew2k1, packR(h1), st);
    st = relu4(st);
    const v4h Bself = packR(st);

    // ---- branches ----
    const v4h Bother = branch_rows<0>(xs, st, ow1t0, ow1t1, ow2k0, ow2k1,
                                      bfrag4(oa_b1, gg), bfrag4(oa_b1 + 16, gg),
                                      bfrag4(oa_b2, gg), bfrag4(oa_g, gg),
                                      bfrag4(oa_bln, gg), lane);
    const v4h Bfood  = branch_rows<1>(xs, st, fw1t0, fw1t1, fw2k0, fw2k1,
                                      bfrag4(g_b1, gg), bfrag4(g_b1 + 16, gg),
                                      bfrag4(g_b2, gg), bfrag4(g_g, gg),
                                      bfrag4(g_bln, gg), lane);

    // ---- merge MLP (N=row): 48 -> 32 lrelu -> 32 lrelu -> 2 tanh ----
    v4f h1t0 = bfrag4(m_b1, gg);
    v4f h1t1 = bfrag4(m_b1 + 16, gg);
    h1t0 = MFMA(afragT(m_w1, 32, 0, 48, 0, lane, 32), Bself, h1t0);
    h1t0 = MFMA(afragT(m_w1, 32, 0, 48, 16, lane, 32), Bfood, h1t0);
    h1t0 = MFMA(afragT(m_w1, 32, 0, 48, 32, lane, 32), Bother, h1t0);
    h1t1 = MFMA(afragT(m_w1, 32, 16, 48, 0, lane, 32), Bself, h1t1);
    h1t1 = MFMA(afragT(m_w1, 32, 16, 48, 16, lane, 32), Bfood, h1t1);
    h1t1 = MFMA(afragT(m_w1, 32, 16, 48, 32, lane, 32), Bother, h1t1);
    const v4h q0 = packL(h1t0), q1 = packL(h1t1);
    v4f h2t0 = bfrag4(m_b2, gg);
    v4f h2t1 = bfrag4(m_b2 + 16, gg);
    h2t0 = MFMA(afragT(m_w2, 32, 0, 32, 0, lane, 32), q0, h2t0);
    h2t0 = MFMA(afragT(m_w2, 32, 0, 32, 16, lane, 32), q1, h2t0);
    h2t1 = MFMA(afragT(m_w2, 32, 16, 32, 0, lane, 32), q0, h2t1);
    h2t1 = MFMA(afragT(m_w2, 32, 16, 32, 16, lane, 32), q1, h2t1);
    const v4h z0 = packL(h2t0), z1 = packL(h2t1);
    v4f ob; ob[0] = ob[1] = ob[2] = ob[3] = 0.f;
    if (gg == 0) { ob[0] = m_b3[0]; ob[1] = m_b3[1]; }
    v4f oo = MFMA(afragT(m_w3, 2, 0, 32, 0, lane, 2), z0, ob);
    oo = MFMA(afragT(m_w3, 2, 0, 32, 16, lane, 2), z1, oo);

    if (gg == 0 && r0 + mm < B) {
        float2 res;
        res.x = fast_tanh(oo[0]);
        res.y = fast_tanh(oo[1]);
        *(float2*)(out + (size_t)(r0 + mm) * 2) = res;
    }
}

extern "C" void kernel_launch(void* const* d_in, const int* in_sizes, int n_in,
                              void* d_out, int out_size, void* d_ws, size_t ws_size,
                              hipStream_t stream) {
    const int B = in_sizes[0] / OBS;
    const float* xin = (const float*)d_in[0];
    const float* en_w1 = (const float*)d_in[1];
    const float* en_b1 = (const float*)d_in[2];
    const float* en_w2 = (const float*)d_in[3];
    const float* en_b2 = (const float*)d_in[4];
    const float* oa_w1 = (const float*)d_in[5];
    const float* oa_b1 = (const float*)d_in[6];
    const float* oa_w2 = (const float*)d_in[7];
    const float* oa_b2 = (const float*)d_in[8];
    const float* oa_g  = (const float*)d_in[9];
    const float* oa_bl = (const float*)d_in[10];
    const float* g_w1  = (const float*)d_in[11];
    const float* g_b1  = (const float*)d_in[12];
    const float* g_w2  = (const float*)d_in[13];
    const float* g_b2  = (const float*)d_in[14];
    const float* g_g   = (const float*)d_in[15];
    const float* g_bl  = (const float*)d_in[16];
    const float* m_w1  = (const float*)d_in[17];
    const float* m_b1  = (const float*)d_in[18];
    const float* m_w2  = (const float*)d_in[19];
    const float* m_b2  = (const float*)d_in[20];
    const float* m_w3  = (const float*)d_in[21];
    const float* m_b3  = (const float*)d_in[22];

    const int rows_per_block = 64;   // 4 waves x 16 rows
    const int grid = (B + rows_per_block - 1) / rows_per_block;
    actor_mfma<<<grid, 256, 0, stream>>>(
        xin, en_w1, en_b1, en_w2, en_b2,
        oa_w1, oa_b1, oa_w2, oa_b2, oa_g, oa_bl,
        g_w1, g_b1, g_w2, g_b2, g_g, g_bl,
        m_w1, m_b1, m_w2, m_b2, m_w3, m_b3,
        (float*)d_out, B);
}